// Round 3
// baseline (351.607 us; speedup 1.0000x reference)
//
#include <hip/hip_runtime.h>
#include <math.h>

// Problem constants: h [B,T,D] fp32, k scalar fp32.
#define BB 8
#define TT 2048
#define DD 512
#define LL 16            // chunk length along T (16 float4/lane -> registers)
#define CC (TT / LL)     // 128 chunks
#define D4 (DD / 4)      // 128 float4 lanes = block size

__device__ __forceinline__ float get_s(const float* kp) {
    float k = *kp;
    return (k > 20.0f) ? k : log1pf(expf(k));   // softplus, stable
}

// Single-pass decoupled-lookback fused kernel.
// Per (b,c): load chunk (registers), publish aggregates (flag=1), lookback
// over predecessors for exact carries, publish inclusive prefix (flag=2),
// then compute mags + ctx + output. h is read exactly once.
__global__ __launch_bounds__(D4) void k_fused(
    const float* __restrict__ h, const float* __restrict__ kp,
    float* __restrict__ csum, float* __restrict__ cend,
    float* __restrict__ psum, float* __restrict__ pend,
    int*   __restrict__ flags,
    float* __restrict__ out)
{
    const int blk = blockIdx.x;
    const int b = blk / CC, c = blk % CC;
    const int tid = threadIdx.x;
    const int wave = tid >> 6, lane = tid & 63;
    const float s  = get_s(kp);
    const float a  = expf(-s);
    const float aL = expf(-s * (float)LL);     // a^L

    const int t0 = c * LL;
    const float4* hp = reinterpret_cast<const float4*>(h)
                     + (size_t)(b * TT + t0) * D4 + tid;

    // issue the h[t0-1] load early to hide latency behind the scan
    float px = 0.f, py = 0.f, pz = 0.f, pw = 0.f;
    if (t0 > 0) {
        float4 pv = hp[-(size_t)D4];
        px = pv.x; py = pv.y; pz = pv.z; pw = pv.w;
    }

    float4 x[LL];
    #pragma unroll
    for (int i = 0; i < LL; i++) x[i] = hp[(size_t)i * D4];

    // ---- chunk aggregates: S = sum, E = locally-decayed end
    float sx = 0.f, sy = 0.f, sz = 0.f, sw = 0.f;
    float ex = 0.f, ey = 0.f, ez = 0.f, ew = 0.f;
    #pragma unroll
    for (int i = 0; i < LL; i++) {
        sx += x[i].x; sy += x[i].y; sz += x[i].z; sw += x[i].w;
        ex = fmaf(a, ex, x[i].x);
        ey = fmaf(a, ey, x[i].y);
        ez = fmaf(a, ez, x[i].z);
        ew = fmaf(a, ew, x[i].w);
    }

    const size_t ci = (size_t)blk * D4 + tid;

    // ---- publish aggregates (flag=1) so successors can make progress
    if (c > 0) {
        reinterpret_cast<float4*>(csum)[ci] = make_float4(sx, sy, sz, sw);
        reinterpret_cast<float4*>(cend)[ci] = make_float4(ex, ey, ez, ew);
        __syncthreads();                       // all payload stores drained (vmcnt 0)
        if (tid == 0)
            __hip_atomic_store(flags + blk, 1, __ATOMIC_RELEASE,
                               __HIP_MEMORY_SCOPE_AGENT);
    }

    // ---- lookback: exact exclusive carries (per-thread independent walk)
    float cox = 0.f, coy = 0.f, coz = 0.f, cow = 0.f;   // cumsum offset
    float ccx = 0.f, ccy = 0.f, ccz = 0.f, ccw = 0.f;   // ctx entering state
    if (c > 0) {
        float w = 1.f;
        for (int cp = c - 1; cp >= 0; --cp) {
            const int fidx = b * CC + cp;
            int f = __hip_atomic_load(flags + fidx, __ATOMIC_ACQUIRE,
                                      __HIP_MEMORY_SCOPE_AGENT);
            while (f == 0) {
                __builtin_amdgcn_s_sleep(1);
                f = __hip_atomic_load(flags + fidx, __ATOMIC_ACQUIRE,
                                      __HIP_MEMORY_SCOPE_AGENT);
            }
            const size_t pi = (size_t)fidx * D4 + tid;
            if (f == 2) {   // inclusive prefix available: consume and stop
                float4 pv = reinterpret_cast<const float4*>(psum)[pi];
                float4 yv = reinterpret_cast<const float4*>(pend)[pi];
                cox += pv.x; coy += pv.y; coz += pv.z; cow += pv.w;
                ccx = fmaf(w, yv.x, ccx);
                ccy = fmaf(w, yv.y, ccy);
                ccz = fmaf(w, yv.z, ccz);
                ccw = fmaf(w, yv.w, ccw);
                break;
            } else {        // aggregate only: accumulate and continue
                float4 sv = reinterpret_cast<const float4*>(csum)[pi];
                float4 ev = reinterpret_cast<const float4*>(cend)[pi];
                cox += sv.x; coy += sv.y; coz += sv.z; cow += sv.w;
                ccx = fmaf(w, ev.x, ccx);
                ccy = fmaf(w, ev.y, ccy);
                ccz = fmaf(w, ev.z, ccz);
                ccw = fmaf(w, ev.w, ccw);
                w *= aL;
            }
        }
    }

    // ---- publish inclusive prefix (flag=2)
    reinterpret_cast<float4*>(psum)[ci] =
        make_float4(cox + sx, coy + sy, coz + sz, cow + sw);
    reinterpret_cast<float4*>(pend)[ci] =
        make_float4(fmaf(aL, ccx, ex), fmaf(aL, ccy, ey),
                    fmaf(aL, ccz, ez), fmaf(aL, ccw, ew));
    __syncthreads();
    if (tid == 0)
        __hip_atomic_store(flags + blk, 2, __ATOMIC_RELEASE,
                           __HIP_MEMORY_SCOPE_AGENT);

    // ---- phase A: cumsum + ||delta||^2 shuffle-reduce -> mags
    __shared__ float m2s[2][LL];
    __shared__ float mags[LL];

    #pragma unroll
    for (int i = 0; i < LL; i++) {
        cox += x[i].x; coy += x[i].y; coz += x[i].z; cow += x[i].w;
        float dx = cox - px, dy = coy - py, dz = coz - pz, dw = cow - pw;
        float r = dx * dx + dy * dy + dz * dz + dw * dw;
        px = x[i].x; py = x[i].y; pz = x[i].z; pw = x[i].w;
        #pragma unroll
        for (int m = 32; m > 0; m >>= 1) r += __shfl_xor(r, m, 64);
        if (lane == 0) m2s[wave][i] = r;
    }
    __syncthreads();
    if (tid < LL) mags[tid] = sqrtf(m2s[0][tid] + m2s[1][tid]);
    __syncthreads();

    // ---- phase B: ctx recurrence from registers, write |mag*ctx|
    float4* op = reinterpret_cast<float4*>(out)
               + (size_t)(b * TT + t0) * D4 + tid;
    #pragma unroll
    for (int i = 0; i < LL; i++) {
        ccx = fmaf(a, ccx, x[i].x);
        ccy = fmaf(a, ccy, x[i].y);
        ccz = fmaf(a, ccz, x[i].z);
        ccw = fmaf(a, ccw, x[i].w);
        float m = mags[i];
        op[(size_t)i * D4] = make_float4(fabsf(m * ccx), fabsf(m * ccy),
                                         fabsf(m * ccz), fabsf(m * ccw));
    }
}

extern "C" void kernel_launch(void* const* d_in, const int* in_sizes, int n_in,
                              void* d_out, int out_size, void* d_ws, size_t ws_size,
                              hipStream_t stream) {
    const float* h  = (const float*)d_in[0];
    const float* kp = (const float*)d_in[1];
    float* out = (float*)d_out;

    const size_t NS = (size_t)BB * CC * DD;   // 512K floats = 2 MB each
    float* csum = (float*)d_ws;
    float* cend = csum + NS;
    float* psum = cend + NS;
    float* pend = psum + NS;
    int*   flags = (int*)(pend + NS);         // B*CC ints = 4 KB

    hipMemsetAsync(flags, 0, (size_t)BB * CC * sizeof(int), stream);
    k_fused<<<dim3(BB * CC), dim3(D4), 0, stream>>>(
        h, kp, csum, cend, psum, pend, flags, out);
}